// Round 11
// baseline (86.484 us; speedup 1.0000x reference)
//
#include <hip/hip_runtime.h>
#include <vector>
#include <cmath>
#include <cstdint>

// ---------------------------------------------------------------------------
// Sparse Clebsch-Gordan tensor product, LMAX=5, TAUS=16, BATCH=256.
//
// R11 = R10's LDS-operand compute + phase-swept DENSE store schedule.
// Grid = 1024 blocks = (job-group 0..127) x (batch-lane 0..7). 32 phases:
// in phase p the whole device writes batches p*8..p*8+7 — one dense 7.5 MB
// window sweeping the output in address order (the fillBuffer pattern that
// measures 6.9 TB/s), instead of 1024 private streams scattered over 240 MB
// (R10: 4.16 TB/s). Per phase each block computes its FIXED 3-5-job group
// from an LDS copy of the current batch's F; F double-buffered, loads issued
// before compute / ds_write after (T14), one __syncthreads per phase.
// ---------------------------------------------------------------------------

#define LMAXV 5
#define NTAU 16

static const int CUMT[7] = {0, 16, 64, 144, 256, 400, 576};

constexpr int F4_ROWS  = 288;            // batch's F as f32x4
constexpr int FBYTES   = F4_ROWS * 16;   // 4608 B
constexpr int NBATCH   = 256;
constexpr int F4_PER_B = 457 * 128;
constexpr int BLK      = 256;
constexpr int NJOBS    = 457;
constexpr int NCOEF    = 2211;
constexpr int NGRP     = 128;
constexpr int NPHASE   = 32;             // 256 batches / 8 lanes

typedef float f32x4 __attribute__((ext_vector_type(4)));

// ------------------------- host-side CG table build ------------------------

static double factd(int n) { double r = 1.0; for (int i = 2; i <= n; ++i) r *= (double)i; return r; }

static double cg_coef(int j1, int m1, int j2, int m2, int j, int m) {
    if (m1 + m2 != m) return 0.0;
    double pref = std::sqrt((2.0 * j + 1.0) * factd(j + j1 - j2) * factd(j - j1 + j2) *
                            factd(j1 + j2 - j) / factd(j1 + j2 + j + 1));
    pref *= std::sqrt(factd(j + m) * factd(j - m) * factd(j1 - m1) * factd(j1 + m1) *
                      factd(j2 - m2) * factd(j2 + m2));
    int kmin = std::max(0, std::max(j2 - j - m1, j1 + m2 - j));
    int kmax = std::min(j1 + j2 - j, std::min(j1 - m1, j2 + m2));
    double s = 0.0;
    for (int k = kmin; k <= kmax; ++k) {
        s += ((k & 1) ? -1.0 : 1.0) /
             (factd(k) * factd(j1 + j2 - j - k) * factd(j1 - m1 - k) * factd(j2 + m2 - k) *
              factd(j - j2 + m1 + k) * factd(j - j1 - m2 + k));
    }
    return pref * s;
}

struct Tables { std::vector<int4> jobs; std::vector<float> coeffs; std::vector<uint16_t> grp; };

static const Tables& get_tables() {
    static Tables t = []() {
        Tables t;
        for (int l = 0; l <= LMAXV; ++l) {
            for (int m_idx = 0; m_idx < 2 * l + 1; ++m_idx) {
                int m = m_idx - l;
                for (int l1 = 0; l1 <= LMAXV; ++l1) {
                    for (int l2 = l1; l2 <= LMAXV; ++l2) {
                        if (!(std::abs(l1 - l2) <= l && l <= l1 + l2)) continue;
                        int lo = std::max(-l1, m - l2), hi = std::min(l1, m + l2);
                        int4 jb;
                        // byte offsets into one F copy (f32x4 layout), term k=0
                        jb.x = (CUMT[l1] / 2 + (lo + l1) * 8) * 16;      // a
                        jb.y = (CUMT[l2] / 2 + (m - lo + l2) * 8) * 16;  // v
                        jb.z = hi - lo + 1;                              // cnt <= 11
                        jb.w = (int)t.coeffs.size();                     // coeff off
                        for (int m1 = lo; m1 <= hi; ++m1)
                            t.coeffs.push_back((float)cg_coef(l1, m1, l2, m - m1, l, m));
                        t.jobs.push_back(jb);
                    }
                }
            }
        }
        // greedy partition of 457 jobs into 128 contiguous groups, balanced
        // by term count (compute), leaving >=0 jobs for the rest.
        t.grp.assign(NGRP + 1, 0);
        int total = 0; for (auto& j : t.jobs) total += j.z;      // 2211
        int jpos = 0; long cum = 0;
        for (int g = 0; g < NGRP; ++g) {
            t.grp[g] = (uint16_t)jpos;
            long target = ((long)total * (g + 1) + NGRP / 2) / NGRP;
            while (jpos < NJOBS && cum < target) { cum += t.jobs[jpos].z; ++jpos; }
        }
        t.grp[NGRP] = (uint16_t)NJOBS;
        return t;
    }();
    return t;
}

// --------------------------------- kernel ----------------------------------

#define KBODY(N)                                                              \
    {                                                                         \
        f32x4 a[N], v[N]; float cc[N];                                        \
        _Pragma("unroll")                                                     \
        for (int k = 0; k < N; ++k) {                                         \
            a[k]  = *(const f32x4*)(sFb + ax + k * 128);                      \
            v[k]  = *(const f32x4*)(sFb + vy - k * 128);                      \
            cc[k] = sC[coff + k];                                             \
        }                                                                     \
        _Pragma("unroll")                                                     \
        for (int k = 0; k < N; ++k) {                                         \
            r00 = fmaf(cc[k], a[k].x * v[k].x - a[k].y * v[k].y, r00);        \
            i00 = fmaf(cc[k], a[k].x * v[k].y + a[k].y * v[k].x, i00);        \
            r01 = fmaf(cc[k], a[k].x * v[k].z - a[k].y * v[k].w, r01);        \
            i01 = fmaf(cc[k], a[k].x * v[k].w + a[k].y * v[k].z, i01);        \
            r10 = fmaf(cc[k], a[k].z * v[k].x - a[k].w * v[k].y, r10);        \
            i10 = fmaf(cc[k], a[k].z * v[k].y + a[k].w * v[k].x, i10);        \
            r11 = fmaf(cc[k], a[k].z * v[k].z - a[k].w * v[k].w, r11);        \
            i11 = fmaf(cc[k], a[k].z * v[k].w + a[k].w * v[k].z, i11);        \
        }                                                                     \
    }

__global__ __launch_bounds__(256, 4) void cg_tp_kernel(
    const f32x4* __restrict__ Fs, f32x4* __restrict__ out,
    const int4* __restrict__ jobs, const float* __restrict__ coeffs,
    const uint16_t* __restrict__ grp)
{
    __shared__ f32x4 sF[2][F4_ROWS];     // double-buffered batch F
    __shared__ float sC[NCOEF];
    __shared__ int4  sJ[NJOBS];

    const int tid   = threadIdx.x;
    const int gid   = blockIdx.x & (NGRP - 1);   // job group 0..127
    const int blane = blockIdx.x >> 7;           // batch lane 0..7

    // ---- one-time staging: coeffs, jobs, phase-0 F ----
    for (int t = tid; t < NCOEF; t += BLK) sC[t] = coeffs[t];
    for (int t = tid; t < NJOBS; t += BLK) sJ[t] = jobs[t];
    {
        const f32x4* __restrict__ F0 = Fs + (size_t)blane * F4_ROWS;
        sF[0][tid] = F0[tid];
        if (tid < F4_ROWS - BLK) sF[0][BLK + tid] = F0[BLK + tid];
    }
    __syncthreads();

    const int js = grp[gid], je = grp[gid + 1];

    const int wv   = tid >> 6;          // wave 0..3
    const int lane = tid & 63;
    const int ip   = lane >> 3;         // i-pair 0..7
    const int jp   = lane & 7;          // j-pair 0..7

    for (int p = 0; p < NPHASE; ++p) {
        const int batch = p * 8 + blane;

        // [A] issue next phase's F loads early (latency hides under compute)
        f32x4 r0, r1;
        if (p < NPHASE - 1) {
            const f32x4* __restrict__ Fn = Fs + (size_t)(batch + 8) * F4_ROWS;
            r0 = Fn[tid];
            if (tid < F4_ROWS - BLK) r1 = Fn[BLK + tid];
        }

        // [B] compute this block's job group from sF[p&1]
        const char* __restrict__ sFb = (const char*)&sF[p & 1][0];
        f32x4* __restrict__ outb = out + (size_t)batch * F4_PER_B;

        for (int jj = js + wv; jj < je; jj += 4) {
            const int4 jbv = sJ[jj];
            const int ax   = __builtin_amdgcn_readfirstlane(jbv.x) + ip * 16;
            const int vy   = __builtin_amdgcn_readfirstlane(jbv.y) + jp * 16;
            const int cnt  = __builtin_amdgcn_readfirstlane(jbv.z);
            const int coff = __builtin_amdgcn_readfirstlane(jbv.w);

            float r00 = 0.f, i00 = 0.f, r01 = 0.f, i01 = 0.f;
            float r10 = 0.f, i10 = 0.f, r11 = 0.f, i11 = 0.f;

            switch (cnt) {
                case 1:  KBODY(1)  break;
                case 2:  KBODY(2)  break;
                case 3:  KBODY(3)  break;
                case 4:  KBODY(4)  break;
                case 5:  KBODY(5)  break;
                case 6:  KBODY(6)  break;
                case 7:  KBODY(7)  break;
                case 8:  KBODY(8)  break;
                case 9:  KBODY(9)  break;
                case 10: KBODY(10) break;
                default: KBODY(11) break;
            }

            f32x4 s0; s0.x = r00; s0.y = i00; s0.z = r01; s0.w = i01;
            f32x4 s1; s1.x = r10; s1.y = i10; s1.z = r11; s1.w = i11;
            f32x4* __restrict__ po = outb + (size_t)jj * 128 + ip * 16 + jp;
            po[0] = s0;          // row i = 2ip   (full 128B lines)
            po[8] = s1;          // row i = 2ip+1
        }

        // [C] write next F into the other buffer (prev readers of it were
        // separated by the previous phase's barrier)
        if (p < NPHASE - 1) {
            sF[(p + 1) & 1][tid] = r0;
            if (tid < F4_ROWS - BLK) sF[(p + 1) & 1][BLK + tid] = r1;
        }
        // [E] single barrier per phase
        __syncthreads();
    }
}

// ------------------------------ entry point --------------------------------

extern "C" void kernel_launch(void* const* d_in, const int* in_sizes, int n_in,
                              void* d_out, int out_size, void* d_ws, size_t ws_size,
                              hipStream_t stream) {
    const Tables& t = get_tables();

    char*     ws       = (char*)d_ws;
    int4*     d_jobs   = (int4*)ws;                          // 7312 B
    size_t    coff     = (NJOBS * sizeof(int4) + 255) & ~(size_t)255;
    float*    d_coeffs = (float*)(ws + coff);                // 8844 B
    size_t    goff     = (coff + NCOEF * sizeof(float) + 255) & ~(size_t)255;
    uint16_t* d_grp    = (uint16_t*)(ws + goff);             // 258 B

    hipMemcpyAsync(d_jobs, t.jobs.data(), t.jobs.size() * sizeof(int4),
                   hipMemcpyHostToDevice, stream);
    hipMemcpyAsync(d_coeffs, t.coeffs.data(), t.coeffs.size() * sizeof(float),
                   hipMemcpyHostToDevice, stream);
    hipMemcpyAsync(d_grp, t.grp.data(), t.grp.size() * sizeof(uint16_t),
                   hipMemcpyHostToDevice, stream);

    const f32x4* Fs  = (const f32x4*)d_in[0];
    f32x4*       out = (f32x4*)d_out;

    cg_tp_kernel<<<NGRP * 8, BLK, 0, stream>>>(Fs, out, d_jobs, d_coeffs, d_grp);
}

// Round 12
// 66.557 us; speedup vs baseline: 1.2994x; 1.2994x over previous
//
#include <hip/hip_runtime.h>
#include <vector>
#include <cmath>
#include <cstdint>

// ---------------------------------------------------------------------------
// Sparse Clebsch-Gordan tensor product, LMAX=5, TAUS=16, BATCH=256.
//
// R12 = R10's compute structure (LDS operands, 2x2 micro-tile, contiguous
// per-job store tiles) with 4x fewer / longer write streams:
//   512 blocks = 256 batches x 2 term-balanced job chunks, 512 threads
//   (8 waves). Device-wide concurrent write streams: 2048 -> 512 (~2 per
//   HBM pseudo-channel) to recover DRAM row locality; waves/CU stays 16.
// k-loop processed in 4-term quads to keep VGPR <= 128
// (__launch_bounds__(512,4) => 2 blocks/CU guaranteed).
// ---------------------------------------------------------------------------

#define LMAXV 5
#define NTAU 16

static const int CUMT[7] = {0, 16, 64, 144, 256, 400, 576};

constexpr int F4_ROWS  = 288;            // batch's F as f32x4
constexpr int NBATCH   = 256;
constexpr int F4_PER_B = 457 * 128;
constexpr int BLK      = 512;
constexpr int NJOBS    = 457;
constexpr int NCOEF    = 2211;

typedef float f32x4 __attribute__((ext_vector_type(4)));

// ------------------------- host-side CG table build ------------------------

static double factd(int n) { double r = 1.0; for (int i = 2; i <= n; ++i) r *= (double)i; return r; }

static double cg_coef(int j1, int m1, int j2, int m2, int j, int m) {
    if (m1 + m2 != m) return 0.0;
    double pref = std::sqrt((2.0 * j + 1.0) * factd(j + j1 - j2) * factd(j - j1 + j2) *
                            factd(j1 + j2 - j) / factd(j1 + j2 + j + 1));
    pref *= std::sqrt(factd(j + m) * factd(j - m) * factd(j1 - m1) * factd(j1 + m1) *
                      factd(j2 - m2) * factd(j2 + m2));
    int kmin = std::max(0, std::max(j2 - j - m1, j1 + m2 - j));
    int kmax = std::min(j1 + j2 - j, std::min(j1 - m1, j2 + m2));
    double s = 0.0;
    for (int k = kmin; k <= kmax; ++k) {
        s += ((k & 1) ? -1.0 : 1.0) /
             (factd(k) * factd(j1 + j2 - j - k) * factd(j1 - m1 - k) * factd(j2 + m2 - k) *
              factd(j - j2 + m1 + k) * factd(j - j1 - m2 + k));
    }
    return pref * s;
}

struct Tables { std::vector<int4> jobs; std::vector<float> coeffs; int split; };

static const Tables& get_tables() {
    static Tables t = []() {
        Tables t;
        for (int l = 0; l <= LMAXV; ++l) {
            for (int m_idx = 0; m_idx < 2 * l + 1; ++m_idx) {
                int m = m_idx - l;
                for (int l1 = 0; l1 <= LMAXV; ++l1) {
                    for (int l2 = l1; l2 <= LMAXV; ++l2) {
                        if (!(std::abs(l1 - l2) <= l && l <= l1 + l2)) continue;
                        int lo = std::max(-l1, m - l2), hi = std::min(l1, m + l2);
                        int4 jb;
                        // byte offsets into sF (f32x4 layout), term k=0
                        jb.x = (CUMT[l1] / 2 + (lo + l1) * 8) * 16;      // a
                        jb.y = (CUMT[l2] / 2 + (m - lo + l2) * 8) * 16;  // v
                        jb.z = hi - lo + 1;                              // cnt <= 11
                        jb.w = (int)t.coeffs.size();                     // coeff off
                        for (int m1 = lo; m1 <= hi; ++m1)
                            t.coeffs.push_back((float)cg_coef(l1, m1, l2, m - m1, l, m));
                        t.jobs.push_back(jb);
                    }
                }
            }
        }
        // term-balanced contiguous split of the 457 jobs into 2 chunks
        int total = 0; for (auto& j : t.jobs) total += j.z;   // 2211
        int cum = 0, s = 0;
        for (int j = 0; j < NJOBS; ++j) { cum += t.jobs[j].z; if (cum * 2 >= total) { s = j + 1; break; } }
        t.split = s;
        return t;
    }();
    return t;
}

// --------------------------------- kernel ----------------------------------

// one quad (N = 1..4 terms at scalar base offsets axq/vyq/coq)
#define QBODY(N)                                                              \
    {                                                                         \
        f32x4 a[N], v[N]; float cc[N];                                        \
        _Pragma("unroll")                                                     \
        for (int k = 0; k < N; ++k) {                                         \
            a[k]  = *(const f32x4*)(sFb + axq + k * 128);                     \
            v[k]  = *(const f32x4*)(sFb + vyq - k * 128);                     \
            cc[k] = sC[coq + k];                                              \
        }                                                                     \
        _Pragma("unroll")                                                     \
        for (int k = 0; k < N; ++k) {                                         \
            r00 = fmaf(cc[k], a[k].x * v[k].x - a[k].y * v[k].y, r00);        \
            i00 = fmaf(cc[k], a[k].x * v[k].y + a[k].y * v[k].x, i00);        \
            r01 = fmaf(cc[k], a[k].x * v[k].z - a[k].y * v[k].w, r01);        \
            i01 = fmaf(cc[k], a[k].x * v[k].w + a[k].y * v[k].z, i01);        \
            r10 = fmaf(cc[k], a[k].z * v[k].x - a[k].w * v[k].y, r10);        \
            i10 = fmaf(cc[k], a[k].z * v[k].y + a[k].w * v[k].x, i10);        \
            r11 = fmaf(cc[k], a[k].z * v[k].z - a[k].w * v[k].w, r11);        \
            i11 = fmaf(cc[k], a[k].z * v[k].w + a[k].w * v[k].z, i11);        \
        }                                                                     \
    }

__global__ __launch_bounds__(512, 4) void cg_tp_kernel(
    const f32x4* __restrict__ Fs, f32x4* __restrict__ out,
    const int4* __restrict__ jobs, const float* __restrict__ coeffs,
    int split)
{
    __shared__ f32x4 sF[F4_ROWS];        // batch's F, natural layout (4.6 KB)
    __shared__ float sC[NCOEF];          // all coeffs (8.8 KB)
    __shared__ int4  sJ[NJOBS];          // all jobs (7.3 KB)

    const int tid   = threadIdx.x;
    const int batch = blockIdx.x >> 1;
    const int chunk = blockIdx.x & 1;

    // ---- stage ----
    {
        const f32x4* __restrict__ Fb4 = Fs + (size_t)batch * F4_ROWS;
        if (tid < F4_ROWS) sF[tid] = Fb4[tid];
        for (int t = tid; t < NCOEF; t += BLK) sC[t] = coeffs[t];
        for (int t = tid; t < NJOBS; t += BLK) sJ[t] = jobs[t];
    }
    __syncthreads();

    const int js = chunk ? split : 0;
    const int je = chunk ? NJOBS : split;

    const int wv   = tid >> 6;          // wave 0..7
    const int lane = tid & 63;
    const int ip   = lane >> 3;         // i-pair 0..7
    const int jp   = lane & 7;          // j-pair 0..7
    const char* __restrict__ sFb = (const char*)sF;

    f32x4* __restrict__ outb = out + (size_t)batch * F4_PER_B;

    for (int jj = js + wv; jj < je; jj += 8) {
        const int4 jbv = sJ[jj];
        const int ax   = __builtin_amdgcn_readfirstlane(jbv.x) + ip * 16;
        const int vy   = __builtin_amdgcn_readfirstlane(jbv.y) + jp * 16;
        const int cnt  = __builtin_amdgcn_readfirstlane(jbv.z);
        const int coff = __builtin_amdgcn_readfirstlane(jbv.w);

        float r00 = 0.f, i00 = 0.f, r01 = 0.f, i01 = 0.f;
        float r10 = 0.f, i10 = 0.f, r11 = 0.f, i11 = 0.f;

        // 4-term quads (VGPR-bounded), then remainder — all branches
        // wave-uniform (cnt is scalar).
        int k0 = 0;
        for (; k0 + 4 <= cnt; k0 += 4) {
            const int axq = ax + k0 * 128, vyq = vy - k0 * 128, coq = coff + k0;
            QBODY(4)
        }
        {
            const int axq = ax + k0 * 128, vyq = vy - k0 * 128, coq = coff + k0;
            switch (cnt - k0) {
                case 1: QBODY(1) break;
                case 2: QBODY(2) break;
                case 3: QBODY(3) break;
                default: break;
            }
        }

        f32x4 s0; s0.x = r00; s0.y = i00; s0.z = r01; s0.w = i01;
        f32x4 s1; s1.x = r10; s1.y = i10; s1.z = r11; s1.w = i11;
        f32x4* __restrict__ po = outb + (size_t)jj * 128 + ip * 16 + jp;
        po[0] = s0;          // row i = 2ip
        po[8] = s1;          // row i = 2ip+1
    }
}

// ------------------------------ entry point --------------------------------

extern "C" void kernel_launch(void* const* d_in, const int* in_sizes, int n_in,
                              void* d_out, int out_size, void* d_ws, size_t ws_size,
                              hipStream_t stream) {
    const Tables& t = get_tables();

    char*  ws       = (char*)d_ws;
    int4*  d_jobs   = (int4*)ws;
    size_t jbytes   = NJOBS * sizeof(int4);
    size_t coff     = (jbytes + 255) & ~(size_t)255;
    float* d_coeffs = (float*)(ws + coff);

    hipMemcpyAsync(d_jobs, t.jobs.data(), jbytes, hipMemcpyHostToDevice, stream);
    hipMemcpyAsync(d_coeffs, t.coeffs.data(), t.coeffs.size() * sizeof(float),
                   hipMemcpyHostToDevice, stream);

    const f32x4* Fs  = (const f32x4*)d_in[0];
    f32x4*       out = (f32x4*)d_out;

    cg_tp_kernel<<<NBATCH * 2, BLK, 0, stream>>>(Fs, out, d_jobs, d_coeffs, t.split);
}